// Round 4
// baseline (223.732 us; speedup 1.0000x reference)
//
#include <hip/hip_runtime.h>
#include <math.h>

#define NF 64
#define NC 16
#define LEN 2048
#define BATCH 256
#define BETA 2.5f
#define KAPPA 10.0f
#define EPSN 1e-12f
#define LOG2E 1.4426950408889634f

#define SPLIT 2
#define HALF (LEN / SPLIT)          // 1024 t's per block
#define TPB 1024
#define NQ (TPB / NF)               // 16 waves per block
#define NS (SPLIT * NQ)             // 32 partials per (b,f)
#define CHUNK (HALF / NQ)           // 64 t's per thread
#define CHUNK_MONO (LEN / NQ)

__device__ __forceinline__ float clip01(float v) { return fminf(fmaxf(v, 0.0f), 1.0f); }

__device__ __forceinline__ float fexp2(float x) {
#if __has_builtin(__builtin_amdgcn_exp2f)
    return __builtin_amdgcn_exp2f(x);
#else
    return exp2f(x);
#endif
}

// ---------------------------------------------------------------------------
// Kernel 1: blocks 0..127 fill lwT4[(t>>2)*NF+f][t&3] = log2(w(f,t)+eps)
// (one float4 per thread, coalesced); block 128 computes reg -> out[BATCH]
// and zeros the per-b atomic counters.
// ---------------------------------------------------------------------------
#define LW_BLOCKS ((NF * LEN / 4) / 256)   // 128

__global__ __launch_bounds__(256) void lw_reg_kernel(
    const float* __restrict__ t1, const float* __restrict__ t2,
    const float* __restrict__ p1, const float* __restrict__ p2,
    const float* __restrict__ tvt, const float* __restrict__ tvl1,
    const float* __restrict__ tvl2, float4* __restrict__ lwT4,
    int* __restrict__ cnt, float* __restrict__ out) {
    const int bid = blockIdx.x;
    const int tid = threadIdx.x;

    if (bid == LW_BLOCKS) {
        // zero the atomic counters (256 of them)
        cnt[tid] = 0;
        // ---- reg scalar ----
        __shared__ float red[256];
        float acc = 0.0f;
        for (int i = tid; i < NC * NF; i += 256) {
            float p = clip01(p1[i]);
            acc += 0.01f * (p * (1.0f - p)) + 0.01f * (p * p);
        }
        if (tid < NC) {
            float p = clip01(p2[tid]);
            acc += 0.01f * (p * (1.0f - p)) + 0.01f * (p * p);
        }
        if (tid < NF) {
            float c = clip01(tvt[tid]);
            acc += 0.01f * (c * (1.0f - c));
        }
        if (tid < NC) {
            float c = clip01(tvl1[tid]);
            acc += 0.01f * (c * (1.0f - c));
        }
        if (tid == 0) {
            float c = clip01(tvl2[0]);
            acc += 0.01f * (c * (1.0f - c));
        }
        red[tid] = acc;
        __syncthreads();
        for (int s = 128; s > 0; s >>= 1) {
            if (tid < s) red[tid] += red[tid + s];
            __syncthreads();
        }
        if (tid == 0) out[BATCH] = red[0];
        return;
    }

    // ---- lwT4 fill: thread handles (f, t-group g) = 4 consecutive t ----
    int idx = bid * 256 + tid;          // idx = g*NF + f
    int f = idx & (NF - 1);
    int g = idx >> 6;
    float t1c = fminf(fmaxf(t1[f], 0.0f), (float)(LEN - 1));
    float t2c = fminf(fmaxf(t2[f], 0.0f), (float)(LEN - 1));
    t1c = fminf(t1c, t2c - 1.0f);
    float4 r;
#pragma unroll
    for (int j = 0; j < 4; ++j) {
        float t = (float)(4 * g + j);
        float su = 1.0f / (1.0f + __expf(-BETA * (t - t1c)));
        float sv = 1.0f / (1.0f + __expf(-BETA * (t2c - t)));
        float lw = __log2f(su * sv + EPSN);
        ((float*)&r)[j] = lw;
    }
    lwT4[idx] = r;
}

// ---------------------------------------------------------------------------
// Kernel 2 (fused): grid = BATCH*SPLIT x 1024.
//  - inner loop: S± = sum w*2^(±A2*x), X± = sum w*2^(±A2*x)*x  (b folded out
//    of the exponent by softmax shift-invariance; r = a*X/S - b at the end)
//  - per-wave partial float4 -> ws
//  - last block per b (device atomic) runs the finish (single wave, no
//    barriers): combine partials -> r1[f], stage2 (4 lanes/clause + shfl
//    reduce), stage3 -> out[b].
// ---------------------------------------------------------------------------
__global__ __launch_bounds__(TPB) void main_fused(
    const float* __restrict__ x, const float* __restrict__ av,
    const float* __restrict__ bv, const float4* __restrict__ lwT4,
    float4* __restrict__ part, int* __restrict__ cnt,
    const float* __restrict__ p1, const float* __restrict__ p2,
    const float* __restrict__ tvt_, const float* __restrict__ tvl1_,
    const float* __restrict__ tvl2_, float* __restrict__ out) {
    const int b = blockIdx.x >> 1;
    const int h = blockIdx.x & 1;
    const int tid = threadIdx.x;
    const int f = tid & (NF - 1);
    const int q = tid >> 6;
    const int ch = f & 1;

    const float a = av[f];
    const float A2 = (BETA * LOG2E) * a;

    const int t0 = h * HALF + q * CHUNK;
    const float* xp = x + (size_t)b * (LEN * 2) + 2 * t0 + ch;
    const float4* lw4 = lwT4 + (t0 >> 2) * NF + f;

    float Sp = 0.f, Xp = 0.f, Sm = 0.f, Xm = 0.f;
#pragma unroll 4
    for (int g = 0; g < CHUNK / 4; ++g) {
        float4 lw = lw4[g * NF];
        float x0 = xp[8 * g + 0];
        float x1 = xp[8 * g + 2];
        float x2 = xp[8 * g + 4];
        float x3 = xp[8 * g + 6];
        float e;
        e = fexp2(fmaf(A2, x0, lw.x)); Sp += e; Xp = fmaf(e, x0, Xp);
        e = fexp2(fmaf(-A2, x0, lw.x)); Sm += e; Xm = fmaf(e, x0, Xm);
        e = fexp2(fmaf(A2, x1, lw.y)); Sp += e; Xp = fmaf(e, x1, Xp);
        e = fexp2(fmaf(-A2, x1, lw.y)); Sm += e; Xm = fmaf(e, x1, Xm);
        e = fexp2(fmaf(A2, x2, lw.z)); Sp += e; Xp = fmaf(e, x2, Xp);
        e = fexp2(fmaf(-A2, x2, lw.z)); Sm += e; Xm = fmaf(e, x2, Xm);
        e = fexp2(fmaf(A2, x3, lw.w)); Sp += e; Xp = fmaf(e, x3, Xp);
        e = fexp2(fmaf(-A2, x3, lw.w)); Sm += e; Xm = fmaf(e, x3, Xm);
    }

    part[((size_t)b * NS + (h * NQ + q)) * NF + f] = make_float4(Sp, Xp, Sm, Xm);

    // ---- last-block-per-b election ----
    __threadfence();                 // release: partials visible device-wide
    __syncthreads();                 // all waves of this block have fenced
    __shared__ int last;
    if (tid == 0) last = (atomicAdd(&cnt[b], 1) == SPLIT - 1) ? 1 : 0;
    __syncthreads();
    if (!last || tid >= 64) return;  // only wave 0 of the last block continues
    __threadfence();                 // acquire: see the other block's partials

    // ---- finish: single wave (64 lanes), no __syncthreads needed ----
    __shared__ float r1s[NF];
    __shared__ float r2s[NC];
    const int l = tid;               // lane = f
    const float KL = KAPPA * LOG2E;

    float4 acc = make_float4(0.f, 0.f, 0.f, 0.f);
    const float4* pb = part + (size_t)b * NS * NF;
#pragma unroll
    for (int s = 0; s < NS; ++s) {
        float4 v = pb[s * NF + l];
        acc.x += v.x; acc.y += v.y; acc.z += v.z; acc.w += v.w;
    }
    {
        float af = av[l], bf = bv[l];
        float tvt = clip01(tvt_[l]);
        float rmax = af * (acc.y / acc.x);
        float rmin = af * (acc.w / acc.z);
        r1s[l] = tvt * rmax + (1.0f - tvt) * rmin - bf;
    }

    // stage 2: lane l -> clause c = l&15, f-quarter j = l>>4
    {
        const int c = l & 15;
        const int j = l >> 4;
        float so = 0.f, wo = 0.f, sa = 0.f, wa = 0.f;
#pragma unroll
        for (int i = 0; i < 16; ++i) {
            int ff = j * 16 + i;
            float r1v = r1s[ff];
            float lg = __log2f(clip01(p1[c * NF + ff]) + EPSN);
            float z = KL * r1v;
            float eo = fexp2(z + lg);
            float ea = fexp2(lg - z);
            so += eo; wo = fmaf(eo, r1v, wo);
            sa += ea; wa = fmaf(ea, r1v, wa);
        }
#pragma unroll
        for (int d = 16; d < 64; d <<= 1) {
            so += __shfl_xor(so, d);
            wo += __shfl_xor(wo, d);
            sa += __shfl_xor(sa, d);
            wa += __shfl_xor(wa, d);
        }
        if (l < NC) {
            float tvl1 = clip01(tvl1_[l]);
            r2s[l] = tvl1 * (wo / so) + (1.0f - tvl1) * (wa / sa);
        }
    }

    // stage 3: lane 0
    if (l == 0) {
        float so = 0.f, wo = 0.f, sa = 0.f, wa = 0.f;
#pragma unroll
        for (int c = 0; c < NC; ++c) {
            float lg = __log2f(clip01(p2[c]) + EPSN);
            float r2v = r2s[c];
            float z = KL * r2v;
            float eo = fexp2(z + lg);
            float ea = fexp2(lg - z);
            so += eo; wo = fmaf(eo, r2v, wo);
            sa += ea; wa = fmaf(ea, r2v, wa);
        }
        float tvl2 = clip01(tvl2_[0]);
        out[b] = tvl2 * (wo / so) + (1.0f - tvl2) * (wa / sa);
    }
}

// ---------------------------------------------------------------------------
// Fallback (mono) kernel + reg: no workspace needed.
// ---------------------------------------------------------------------------
__global__ __launch_bounds__(TPB) void main_mono(
    const float* __restrict__ x, const float* __restrict__ av,
    const float* __restrict__ bv,
    const float* __restrict__ t1g, const float* __restrict__ t2g,
    const float* __restrict__ p1, const float* __restrict__ p2,
    const float* __restrict__ tvt_, const float* __restrict__ tvl1_,
    const float* __restrict__ tvl2_, float* __restrict__ out) {
    __shared__ float4 redQ[NQ][NF];
    __shared__ float lp[NC][NF];
    __shared__ float r1s[NF];
    __shared__ float r2s[NC];

    const int b = blockIdx.x;
    const int tid = threadIdx.x;
    const int f = tid & (NF - 1);
    const int q = tid >> 6;
    const float B2 = BETA * LOG2E;
    const float KL = KAPPA * LOG2E;

    const float a = av[f];
    const float bb = bv[f];
    const int ch = f & 1;

    float t1c = fminf(fmaxf(t1g[f], 0.0f), (float)(LEN - 1));
    float t2c = fminf(fmaxf(t2g[f], 0.0f), (float)(LEN - 1));
    t1c = fminf(t1c, t2c - 1.0f);

    const int t0 = q * CHUNK_MONO;
    const float* xp = x + (size_t)b * (LEN * 2) + 2 * t0 + ch;
    float sp = 0.f, wp = 0.f, sm = 0.f, wm = 0.f;
#pragma unroll 8
    for (int k = 0; k < CHUNK_MONO; ++k) {
        int t = t0 + k;
        float su = 1.0f / (1.0f + __expf(-BETA * ((float)t - t1c)));
        float sv = 1.0f / (1.0f + __expf(-BETA * (t2c - (float)t)));
        float lw2 = __log2f(su * sv + EPSN);
        float xv = xp[2 * k];
        float rp = fmaf(a, xv, -bb);
        float ep = fexp2(fmaf(B2, rp, lw2));
        float em = fexp2(fmaf(-B2, rp, lw2));
        sp += ep; wp = fmaf(ep, rp, wp);
        sm += em; wm = fmaf(em, rp, wm);
    }
    redQ[q][f] = make_float4(sp, wp, sm, wm);
    {
        float pv = clip01(p1[tid]);
        ((float*)lp)[tid] = __log2f(pv + EPSN);
    }
    __syncthreads();

    if (q == 0) {
        float Sp = 0.f, Wp = 0.f, Sm = 0.f, Wm = 0.f;
#pragma unroll
        for (int j = 0; j < NQ; ++j) {
            float4 v = redQ[j][f];
            Sp += v.x; Wp += v.y; Sm += v.z; Wm += v.w;
        }
        float tvt = clip01(tvt_[f]);
        r1s[f] = tvt * (Wp / Sp) + (1.0f - tvt) * (Wm / Sm);
    }
    __syncthreads();

    if (tid < NC) {
        const int c = tid;
        float so = 0.f, wo = 0.f, sa = 0.f, wa = 0.f;
#pragma unroll
        for (int ff = 0; ff < NF; ++ff) {
            float r1v = r1s[ff];
            float z = KL * r1v;
            float lg = lp[c][ff];
            float eo = fexp2(z + lg);
            float ea = fexp2(lg - z);
            so += eo; wo = fmaf(eo, r1v, wo);
            sa += ea; wa = fmaf(ea, r1v, wa);
        }
        float tvl1 = clip01(tvl1_[c]);
        r2s[c] = tvl1 * (wo / so) + (1.0f - tvl1) * (wa / sa);
    }
    __syncthreads();

    if (tid == 0) {
        float so = 0.f, wo = 0.f, sa = 0.f, wa = 0.f;
#pragma unroll
        for (int c = 0; c < NC; ++c) {
            float lg = __log2f(clip01(p2[c]) + EPSN);
            float r2v = r2s[c];
            float z = KL * r2v;
            float eo = fexp2(z + lg);
            float ea = fexp2(lg - z);
            so += eo; wo = fmaf(eo, r2v, wo);
            sa += ea; wa = fmaf(ea, r2v, wa);
        }
        float tvl2 = clip01(tvl2_[0]);
        out[b] = tvl2 * (wo / so) + (1.0f - tvl2) * (wa / sa);
    }
}

__global__ void reg_kernel(const float* __restrict__ p1, const float* __restrict__ p2,
                           const float* __restrict__ tvt, const float* __restrict__ tvl1,
                           const float* __restrict__ tvl2, float* __restrict__ out) {
    __shared__ float red[256];
    int tid = threadIdx.x;
    float acc = 0.0f;
    for (int i = tid; i < NC * NF; i += 256) {
        float p = clip01(p1[i]);
        acc += 0.01f * (p * (1.0f - p)) + 0.01f * (p * p);
    }
    if (tid < NC) {
        float p = clip01(p2[tid]);
        acc += 0.01f * (p * (1.0f - p)) + 0.01f * (p * p);
    }
    if (tid < NF) {
        float c = clip01(tvt[tid]);
        acc += 0.01f * (c * (1.0f - c));
    }
    if (tid < NC) {
        float c = clip01(tvl1[tid]);
        acc += 0.01f * (c * (1.0f - c));
    }
    if (tid == 0) {
        float c = clip01(tvl2[0]);
        acc += 0.01f * (c * (1.0f - c));
    }
    red[tid] = acc;
    __syncthreads();
    for (int s = 128; s > 0; s >>= 1) {
        if (tid < s) red[tid] += red[tid + s];
        __syncthreads();
    }
    if (tid == 0) out[BATCH] = red[0];
}

// ---------------------------------------------------------------------------
extern "C" void kernel_launch(void* const* d_in, const int* in_sizes, int n_in,
                              void* d_out, int out_size, void* d_ws, size_t ws_size,
                              hipStream_t stream) {
    const float* x    = (const float*)d_in[0];
    const float* t1   = (const float*)d_in[1];
    const float* t2   = (const float*)d_in[2];
    const float* a    = (const float*)d_in[3];
    const float* bv   = (const float*)d_in[4];
    const float* p1   = (const float*)d_in[5];
    const float* p2   = (const float*)d_in[6];
    const float* tvt  = (const float*)d_in[7];
    const float* tvl1 = (const float*)d_in[8];
    const float* tvl2 = (const float*)d_in[9];
    float* out = (float*)d_out;

    const size_t lw_bytes = (size_t)(NF * LEN) * sizeof(float);              // 512 KB
    const size_t part_bytes = (size_t)BATCH * NS * NF * sizeof(float4);      // 8 MB
    const size_t cnt_bytes = (size_t)BATCH * sizeof(int);                    // 1 KB

    if (d_ws && ws_size >= lw_bytes + part_bytes + cnt_bytes) {
        float4* lwT4 = (float4*)d_ws;
        float4* part = (float4*)((char*)d_ws + lw_bytes);
        int* cnt = (int*)((char*)d_ws + lw_bytes + part_bytes);
        lw_reg_kernel<<<LW_BLOCKS + 1, 256, 0, stream>>>(t1, t2, p1, p2, tvt, tvl1,
                                                         tvl2, lwT4, cnt, out);
        main_fused<<<BATCH * SPLIT, TPB, 0, stream>>>(x, a, bv, lwT4, part, cnt,
                                                      p1, p2, tvt, tvl1, tvl2, out);
    } else {
        main_mono<<<BATCH, TPB, 0, stream>>>(x, a, bv, t1, t2, p1, p2,
                                             tvt, tvl1, tvl2, out);
        reg_kernel<<<1, 256, 0, stream>>>(p1, p2, tvt, tvl1, tvl2, out);
    }
}

// Round 5
// 27.439 us; speedup vs baseline: 8.1537x; 8.1537x over previous
//
#include <hip/hip_runtime.h>
#include <math.h>

#define NF 64
#define NC 16
#define LEN 2048
#define BATCH 256
#define BETA 2.5f
#define KAPPA 10.0f
#define EPSN 1e-12f
#define LOG2E 1.4426950408889634f

// main kernel decomposition: 256-thread blocks (4 waves), 8 t-splits per b
#define TPB 256
#define NQ (TPB / NF)               // 4 waves per block
#define SPLIT 8
#define HALF (LEN / SPLIT)          // 256 t's per block
#define CHUNK (HALF / NQ)           // 64 t's per thread
#define NS (SPLIT * NQ)             // 32 partials per (b,f)

// fallback mono config
#define MTPB 1024
#define MNQ (MTPB / NF)
#define CHUNK_MONO (LEN / MNQ)

__device__ __forceinline__ float clip01(float v) { return fminf(fmaxf(v, 0.0f), 1.0f); }

__device__ __forceinline__ float fexp2(float x) {
#if __has_builtin(__builtin_amdgcn_exp2f)
    return __builtin_amdgcn_exp2f(x);
#else
    return exp2f(x);
#endif
}

// ---------------------------------------------------------------------------
// Kernel 1: blocks 0..127 fill lwT4[g*NF+f] = log2(w(f,4g+j)+eps), j in lane;
//           block 128 computes reg -> out[BATCH].
// ---------------------------------------------------------------------------
#define LW_BLOCKS ((NF * LEN / 4) / 256)   // 128

__global__ __launch_bounds__(256) void lw_reg_kernel(
    const float* __restrict__ t1, const float* __restrict__ t2,
    const float* __restrict__ p1, const float* __restrict__ p2,
    const float* __restrict__ tvt, const float* __restrict__ tvl1,
    const float* __restrict__ tvl2, float4* __restrict__ lwT4,
    float* __restrict__ out) {
    const int bid = blockIdx.x;
    const int tid = threadIdx.x;

    if (bid == LW_BLOCKS) {
        // ---- reg scalar ----
        __shared__ float red[256];
        float acc = 0.0f;
        for (int i = tid; i < NC * NF; i += 256) {
            float p = clip01(p1[i]);
            acc += 0.01f * (p * (1.0f - p)) + 0.01f * (p * p);
        }
        if (tid < NC) {
            float p = clip01(p2[tid]);
            acc += 0.01f * (p * (1.0f - p)) + 0.01f * (p * p);
        }
        if (tid < NF) {
            float c = clip01(tvt[tid]);
            acc += 0.01f * (c * (1.0f - c));
        }
        if (tid < NC) {
            float c = clip01(tvl1[tid]);
            acc += 0.01f * (c * (1.0f - c));
        }
        if (tid == 0) {
            float c = clip01(tvl2[0]);
            acc += 0.01f * (c * (1.0f - c));
        }
        red[tid] = acc;
        __syncthreads();
        for (int s = 128; s > 0; s >>= 1) {
            if (tid < s) red[tid] += red[tid + s];
            __syncthreads();
        }
        if (tid == 0) out[BATCH] = red[0];
        return;
    }

    // ---- lwT4 fill: thread handles (f, t-group g) = 4 consecutive t ----
    int idx = bid * 256 + tid;          // idx = g*NF + f
    int f = idx & (NF - 1);
    int g = idx >> 6;
    float t1c = fminf(fmaxf(t1[f], 0.0f), (float)(LEN - 1));
    float t2c = fminf(fmaxf(t2[f], 0.0f), (float)(LEN - 1));
    t1c = fminf(t1c, t2c - 1.0f);
    float4 r;
#pragma unroll
    for (int j = 0; j < 4; ++j) {
        float t = (float)(4 * g + j);
        float su = 1.0f / (1.0f + __expf(-BETA * (t - t1c)));
        float sv = 1.0f / (1.0f + __expf(-BETA * (t2c - t)));
        ((float*)&r)[j] = __log2f(su * sv + EPSN);
    }
    lwT4[idx] = r;
}

// ---------------------------------------------------------------------------
// Kernel 2: grid = BATCH*SPLIT (2048) x 256. No LDS, no barriers, no fences.
// S± = sum w*2^(±A2*x), X± = sum w*2^(±A2*x)*x  (b folded out of the
// exponent; r = a*X/S - b recovered in finish). Per-wave partial -> ws.
// part layout: part[(b*NS + s)*NF + f], s = h*NQ + q.
// ---------------------------------------------------------------------------
__global__ __launch_bounds__(TPB) void main_split(
    const float* __restrict__ x, const float* __restrict__ av,
    const float4* __restrict__ lwT4, float4* __restrict__ part) {
    const int b = blockIdx.x >> 3;
    const int h = blockIdx.x & 7;
    const int tid = threadIdx.x;
    const int f = tid & (NF - 1);
    const int q = tid >> 6;
    const int ch = f & 1;

    const float A2 = (BETA * LOG2E) * av[f];

    const int t0 = h * HALF + q * CHUNK;
    const float* xp = x + (size_t)b * (LEN * 2) + 2 * t0 + ch;
    const float4* lw4 = lwT4 + (t0 >> 2) * NF + f;

    float Sp0 = 0.f, Xp0 = 0.f, Sm0 = 0.f, Xm0 = 0.f;
    float Sp1 = 0.f, Xp1 = 0.f, Sm1 = 0.f, Xm1 = 0.f;
#pragma unroll 4
    for (int g = 0; g < CHUNK / 4; ++g) {
        float4 lw = lw4[g * NF];
        float x0 = xp[8 * g + 0];
        float x1 = xp[8 * g + 2];
        float x2 = xp[8 * g + 4];
        float x3 = xp[8 * g + 6];
        float e;
        e = fexp2(fmaf(A2, x0, lw.x));  Sp0 += e; Xp0 = fmaf(e, x0, Xp0);
        e = fexp2(fmaf(-A2, x0, lw.x)); Sm0 += e; Xm0 = fmaf(e, x0, Xm0);
        e = fexp2(fmaf(A2, x1, lw.y));  Sp1 += e; Xp1 = fmaf(e, x1, Xp1);
        e = fexp2(fmaf(-A2, x1, lw.y)); Sm1 += e; Xm1 = fmaf(e, x1, Xm1);
        e = fexp2(fmaf(A2, x2, lw.z));  Sp0 += e; Xp0 = fmaf(e, x2, Xp0);
        e = fexp2(fmaf(-A2, x2, lw.z)); Sm0 += e; Xm0 = fmaf(e, x2, Xm0);
        e = fexp2(fmaf(A2, x3, lw.w));  Sp1 += e; Xp1 = fmaf(e, x3, Xp1);
        e = fexp2(fmaf(-A2, x3, lw.w)); Sm1 += e; Xm1 = fmaf(e, x3, Xm1);
    }

    part[((size_t)b * NS + (h * NQ + q)) * NF + f] =
        make_float4(Sp0 + Sp1, Xp0 + Xp1, Sm0 + Sm1, Xm0 + Xm1);
}

// ---------------------------------------------------------------------------
// Kernel 3: grid = BATCH x 64 (single wave). Combine 32 partials -> r1[f];
// stage2 (4 lanes/clause + shfl reduce); stage3 -> out[b].
// Single-pass (no max): |K*log2e*r| <= ~87, log2(p+eps) >= -40 -> exp2 args
// within +-127, no overflow/flush of dominant terms. (Validated: absmax 0.)
// ---------------------------------------------------------------------------
__global__ __launch_bounds__(64) void finish_kernel(
    const float4* __restrict__ part, const float* __restrict__ av,
    const float* __restrict__ bv, const float* __restrict__ p1,
    const float* __restrict__ p2, const float* __restrict__ tvt_,
    const float* __restrict__ tvl1_, const float* __restrict__ tvl2_,
    float* __restrict__ out) {
    __shared__ float r1s[NF];
    __shared__ float r2s[NC];

    const int b = blockIdx.x;
    const int l = threadIdx.x;
    const float KL = KAPPA * LOG2E;

    float ax = 0.f, ay = 0.f, az = 0.f, aw = 0.f;
    const float4* pb = part + (size_t)b * NS * NF;
#pragma unroll
    for (int s = 0; s < NS; ++s) {
        float4 v = pb[s * NF + l];
        ax += v.x; ay += v.y; az += v.z; aw += v.w;
    }
    {
        float af = av[l], bf = bv[l];
        float tvt = clip01(tvt_[l]);
        float rmax = af * (ay / ax);
        float rmin = af * (aw / az);
        r1s[l] = tvt * rmax + (1.0f - tvt) * rmin - bf;
    }

    // stage 2: lane l -> clause c = l&15, f-quarter j = l>>4
    {
        const int c = l & 15;
        const int j = l >> 4;
        float so = 0.f, wo = 0.f, sa = 0.f, wa = 0.f;
#pragma unroll
        for (int i = 0; i < 16; ++i) {
            int ff = j * 16 + i;
            float r1v = r1s[ff];
            float lg = __log2f(clip01(p1[c * NF + ff]) + EPSN);
            float z = KL * r1v;
            float eo = fexp2(z + lg);
            float ea = fexp2(lg - z);
            so += eo; wo = fmaf(eo, r1v, wo);
            sa += ea; wa = fmaf(ea, r1v, wa);
        }
#pragma unroll
        for (int d = 16; d < 64; d <<= 1) {
            so += __shfl_xor(so, d);
            wo += __shfl_xor(wo, d);
            sa += __shfl_xor(sa, d);
            wa += __shfl_xor(wa, d);
        }
        if (l < NC) {
            float tvl1 = clip01(tvl1_[l]);
            r2s[l] = tvl1 * (wo / so) + (1.0f - tvl1) * (wa / sa);
        }
    }

    // stage 3: lane 0
    if (l == 0) {
        float so = 0.f, wo = 0.f, sa = 0.f, wa = 0.f;
#pragma unroll
        for (int c = 0; c < NC; ++c) {
            float lg = __log2f(clip01(p2[c]) + EPSN);
            float r2v = r2s[c];
            float z = KL * r2v;
            float eo = fexp2(z + lg);
            float ea = fexp2(lg - z);
            so += eo; wo = fmaf(eo, r2v, wo);
            sa += ea; wa = fmaf(ea, r2v, wa);
        }
        float tvl2 = clip01(tvl2_[0]);
        out[b] = tvl2 * (wo / so) + (1.0f - tvl2) * (wa / sa);
    }
}

// ---------------------------------------------------------------------------
// Fallback (mono) kernel + reg: no workspace needed.
// ---------------------------------------------------------------------------
__global__ __launch_bounds__(MTPB) void main_mono(
    const float* __restrict__ x, const float* __restrict__ av,
    const float* __restrict__ bv,
    const float* __restrict__ t1g, const float* __restrict__ t2g,
    const float* __restrict__ p1, const float* __restrict__ p2,
    const float* __restrict__ tvt_, const float* __restrict__ tvl1_,
    const float* __restrict__ tvl2_, float* __restrict__ out) {
    __shared__ float4 redQ[MNQ][NF];
    __shared__ float lp[NC][NF];
    __shared__ float r1s[NF];
    __shared__ float r2s[NC];

    const int b = blockIdx.x;
    const int tid = threadIdx.x;
    const int f = tid & (NF - 1);
    const int q = tid >> 6;
    const float B2 = BETA * LOG2E;
    const float KL = KAPPA * LOG2E;

    const float a = av[f];
    const float bb = bv[f];
    const int ch = f & 1;

    float t1c = fminf(fmaxf(t1g[f], 0.0f), (float)(LEN - 1));
    float t2c = fminf(fmaxf(t2g[f], 0.0f), (float)(LEN - 1));
    t1c = fminf(t1c, t2c - 1.0f);

    const int t0 = q * CHUNK_MONO;
    const float* xp = x + (size_t)b * (LEN * 2) + 2 * t0 + ch;
    float sp = 0.f, wp = 0.f, sm = 0.f, wm = 0.f;
#pragma unroll 8
    for (int k = 0; k < CHUNK_MONO; ++k) {
        int t = t0 + k;
        float su = 1.0f / (1.0f + __expf(-BETA * ((float)t - t1c)));
        float sv = 1.0f / (1.0f + __expf(-BETA * (t2c - (float)t)));
        float lw2 = __log2f(su * sv + EPSN);
        float xv = xp[2 * k];
        float rp = fmaf(a, xv, -bb);
        float ep = fexp2(fmaf(B2, rp, lw2));
        float em = fexp2(fmaf(-B2, rp, lw2));
        sp += ep; wp = fmaf(ep, rp, wp);
        sm += em; wm = fmaf(em, rp, wm);
    }
    redQ[q][f] = make_float4(sp, wp, sm, wm);
    {
        float pv = clip01(p1[tid]);
        ((float*)lp)[tid] = __log2f(pv + EPSN);
    }
    __syncthreads();

    if (q == 0) {
        float Sp = 0.f, Wp = 0.f, Sm = 0.f, Wm = 0.f;
#pragma unroll
        for (int j = 0; j < MNQ; ++j) {
            float4 v = redQ[j][f];
            Sp += v.x; Wp += v.y; Sm += v.z; Wm += v.w;
        }
        float tvt = clip01(tvt_[f]);
        r1s[f] = tvt * (Wp / Sp) + (1.0f - tvt) * (Wm / Sm);
    }
    __syncthreads();

    if (tid < NC) {
        const int c = tid;
        float so = 0.f, wo = 0.f, sa = 0.f, wa = 0.f;
#pragma unroll
        for (int ff = 0; ff < NF; ++ff) {
            float r1v = r1s[ff];
            float z = KL * r1v;
            float lg = lp[c][ff];
            float eo = fexp2(z + lg);
            float ea = fexp2(lg - z);
            so += eo; wo = fmaf(eo, r1v, wo);
            sa += ea; wa = fmaf(ea, r1v, wa);
        }
        float tvl1 = clip01(tvl1_[c]);
        r2s[c] = tvl1 * (wo / so) + (1.0f - tvl1) * (wa / sa);
    }
    __syncthreads();

    if (tid == 0) {
        float so = 0.f, wo = 0.f, sa = 0.f, wa = 0.f;
#pragma unroll
        for (int c = 0; c < NC; ++c) {
            float lg = __log2f(clip01(p2[c]) + EPSN);
            float r2v = r2s[c];
            float z = KL * r2v;
            float eo = fexp2(z + lg);
            float ea = fexp2(lg - z);
            so += eo; wo = fmaf(eo, r2v, wo);
            sa += ea; wa = fmaf(ea, r2v, wa);
        }
        float tvl2 = clip01(tvl2_[0]);
        out[b] = tvl2 * (wo / so) + (1.0f - tvl2) * (wa / sa);
    }
}

__global__ void reg_kernel(const float* __restrict__ p1, const float* __restrict__ p2,
                           const float* __restrict__ tvt, const float* __restrict__ tvl1,
                           const float* __restrict__ tvl2, float* __restrict__ out) {
    __shared__ float red[256];
    int tid = threadIdx.x;
    float acc = 0.0f;
    for (int i = tid; i < NC * NF; i += 256) {
        float p = clip01(p1[i]);
        acc += 0.01f * (p * (1.0f - p)) + 0.01f * (p * p);
    }
    if (tid < NC) {
        float p = clip01(p2[tid]);
        acc += 0.01f * (p * (1.0f - p)) + 0.01f * (p * p);
    }
    if (tid < NF) {
        float c = clip01(tvt[tid]);
        acc += 0.01f * (c * (1.0f - c));
    }
    if (tid < NC) {
        float c = clip01(tvl1[tid]);
        acc += 0.01f * (c * (1.0f - c));
    }
    if (tid == 0) {
        float c = clip01(tvl2[0]);
        acc += 0.01f * (c * (1.0f - c));
    }
    red[tid] = acc;
    __syncthreads();
    for (int s = 128; s > 0; s >>= 1) {
        if (tid < s) red[tid] += red[tid + s];
        __syncthreads();
    }
    if (tid == 0) out[BATCH] = red[0];
}

// ---------------------------------------------------------------------------
extern "C" void kernel_launch(void* const* d_in, const int* in_sizes, int n_in,
                              void* d_out, int out_size, void* d_ws, size_t ws_size,
                              hipStream_t stream) {
    const float* x    = (const float*)d_in[0];
    const float* t1   = (const float*)d_in[1];
    const float* t2   = (const float*)d_in[2];
    const float* a    = (const float*)d_in[3];
    const float* bv   = (const float*)d_in[4];
    const float* p1   = (const float*)d_in[5];
    const float* p2   = (const float*)d_in[6];
    const float* tvt  = (const float*)d_in[7];
    const float* tvl1 = (const float*)d_in[8];
    const float* tvl2 = (const float*)d_in[9];
    float* out = (float*)d_out;

    const size_t lw_bytes = (size_t)(NF * LEN) * sizeof(float);              // 512 KB
    const size_t part_bytes = (size_t)BATCH * NS * NF * sizeof(float4);      // 8 MB

    if (d_ws && ws_size >= lw_bytes + part_bytes) {
        float4* lwT4 = (float4*)d_ws;
        float4* part = (float4*)((char*)d_ws + lw_bytes);
        lw_reg_kernel<<<LW_BLOCKS + 1, 256, 0, stream>>>(t1, t2, p1, p2, tvt, tvl1,
                                                         tvl2, lwT4, out);
        main_split<<<BATCH * SPLIT, TPB, 0, stream>>>(x, a, lwT4, part);
        finish_kernel<<<BATCH, 64, 0, stream>>>(part, a, bv, p1, p2, tvt, tvl1,
                                                tvl2, out);
    } else {
        main_mono<<<BATCH, MTPB, 0, stream>>>(x, a, bv, t1, t2, p1, p2,
                                              tvt, tvl1, tvl2, out);
        reg_kernel<<<1, 256, 0, stream>>>(p1, p2, tvt, tvl1, tvl2, out);
    }
}

// Round 6
// 26.901 us; speedup vs baseline: 8.3169x; 1.0200x over previous
//
#include <hip/hip_runtime.h>
#include <math.h>

#define NF 64
#define NC 16
#define LEN 2048
#define BATCH 256
#define BETA 2.5f
#define KAPPA 10.0f
#define EPSN 1e-12f
#define LOG2E 1.4426950408889634f

#define TPB 1024
#define NQ (TPB / NF)        // 16 waves per block
#define CHUNK (LEN / NQ)     // 128 t's per thread

__device__ __forceinline__ float clip01(float v) { return fminf(fmaxf(v, 0.0f), 1.0f); }

__device__ __forceinline__ float fexp2(float x) {
#if __has_builtin(__builtin_amdgcn_exp2f)
    return __builtin_amdgcn_exp2f(x);
#else
    return exp2f(x);
#endif
}

__device__ __forceinline__ float frcp(float x) {
#if __has_builtin(__builtin_amdgcn_rcpf)
    return __builtin_amdgcn_rcpf(x);
#else
    return 1.0f / x;
#endif
}

// ---------------------------------------------------------------------------
// ONE kernel: grid = BATCH x 1024 (16 waves). Per block (one batch element b):
//  stage1: thread (f = tid&63, q = tid>>6) handles 128 t's for feature f.
//    w(f,t) = sig(B(t-t1c))*sig(B(t2c-t)) = rcp((1+2^g1)(1+2^g2)),
//      g1 = B2*(t1c-t), g2 = B2*(t-t2c)   [B2 = BETA*log2e]
//    (2^big -> inf -> w=0; matches ref's w+1e-12 to ~2e-9 relative since
//     [t1c,t2c] always contains w~1 terms)
//    weights for rmax/rmin: w * 2^{+-A2*x}, A2 = BETA*log2e*a[f]  (b[f] and
//    e^{-B*b} fold out of the softmax; r = a*X/S - b recovered in finish).
//  per-wave partial float4 -> LDS; one barrier; wave 0 does finish
//  (combine 16 partials -> r1[f]; stage2 4 lanes/clause + shfl; stage3).
//  block 0 wave 15 computes the reg scalar -> out[BATCH].
// No workspace, no fences, no cross-block traffic.
// ---------------------------------------------------------------------------
__global__ __launch_bounds__(TPB) void fused_kernel(
    const float* __restrict__ x, const float* __restrict__ t1g,
    const float* __restrict__ t2g, const float* __restrict__ av,
    const float* __restrict__ bv, const float* __restrict__ p1,
    const float* __restrict__ p2, const float* __restrict__ tvt_,
    const float* __restrict__ tvl1_, const float* __restrict__ tvl2_,
    float* __restrict__ out) {
    __shared__ float4 redQ[NQ][NF];      // 16 KB
    __shared__ float r1s[NF];
    __shared__ float r2s[NC];

    const int b = blockIdx.x;
    const int tid = threadIdx.x;
    const int f = tid & (NF - 1);
    const int q = tid >> 6;
    const int ch = f & 1;

    const float B2 = BETA * LOG2E;
    const float KL = KAPPA * LOG2E;

    const float a = av[f];
    const float A2 = B2 * a;

    float t1c = fminf(fmaxf(t1g[f], 0.0f), (float)(LEN - 1));
    float t2c = fminf(fmaxf(t2g[f], 0.0f), (float)(LEN - 1));
    t1c = fminf(t1c, t2c - 1.0f);
    const float c1 = B2 * t1c;           // g1 = c1 - B2*t
    const float c2 = -B2 * t2c;          // g2 = B2*t + c2

    const int t0 = q * CHUNK;
    // wave-uniform float4 loads (2 t's per load, broadcast within wave)
    const float4* xp4 = (const float4*)(x + (size_t)b * (LEN * 2) + 2 * t0);

    float Sp0 = 0.f, Xp0 = 0.f, Sm0 = 0.f, Xm0 = 0.f;
    float Sp1 = 0.f, Xp1 = 0.f, Sm1 = 0.f, Xm1 = 0.f;
#pragma unroll 4
    for (int k2 = 0; k2 < CHUNK / 2; ++k2) {
        float4 v = xp4[k2];
        float xa = ch ? v.y : v.x;       // t = t0 + 2*k2
        float xb = ch ? v.w : v.z;       // t = t0 + 2*k2 + 1
        float tfa = (float)(t0 + 2 * k2);
        float tfb = tfa + 1.0f;

        // t even -> accumulator set 0
        {
            float g1 = fmaf(-B2, tfa, c1);
            float g2 = fmaf(B2, tfa, c2);
            float den = (1.0f + fexp2(g1)) * (1.0f + fexp2(g2));
            float w = frcp(den);
            float P = fexp2(A2 * xa);
            float Pm = frcp(P);
            float tp = P * w, tm = Pm * w;
            Sp0 += tp; Xp0 = fmaf(tp, xa, Xp0);
            Sm0 += tm; Xm0 = fmaf(tm, xa, Xm0);
        }
        // t odd -> accumulator set 1
        {
            float g1 = fmaf(-B2, tfb, c1);
            float g2 = fmaf(B2, tfb, c2);
            float den = (1.0f + fexp2(g1)) * (1.0f + fexp2(g2));
            float w = frcp(den);
            float P = fexp2(A2 * xb);
            float Pm = frcp(P);
            float tp = P * w, tm = Pm * w;
            Sp1 += tp; Xp1 = fmaf(tp, xb, Xp1);
            Sm1 += tm; Xm1 = fmaf(tm, xb, Xm1);
        }
    }

    redQ[q][f] = make_float4(Sp0 + Sp1, Xp0 + Xp1, Sm0 + Sm1, Xm0 + Xm1);

    // ---- reg scalar: block 0, wave 15 (independent of stage1 results) ----
    if (b == 0 && q == NQ - 1) {
        const int l = f;
        float acc = 0.0f;
#pragma unroll
        for (int i = 0; i < 16; ++i) {
            float p = clip01(p1[i * NF + l]);
            acc += 0.01f * (p * (1.0f - p)) + 0.01f * (p * p);
        }
        {
            float c = clip01(tvt_[l]);
            acc += 0.01f * (c * (1.0f - c));
        }
        if (l < NC) {
            float p = clip01(p2[l]);
            acc += 0.01f * (p * (1.0f - p)) + 0.01f * (p * p);
            float c = clip01(tvl1_[l]);
            acc += 0.01f * (c * (1.0f - c));
        }
        if (l == 0) {
            float c = clip01(tvl2_[0]);
            acc += 0.01f * (c * (1.0f - c));
        }
#pragma unroll
        for (int d = 1; d < 64; d <<= 1) acc += __shfl_xor(acc, d);
        if (l == 0) out[BATCH] = acc;
    }

    __syncthreads();
    if (tid >= 64) return;

    // ---- finish: single wave (validated in R5), LDS-sourced partials ----
    const int l = tid;
    float ax = 0.f, ay = 0.f, az = 0.f, aw = 0.f;
#pragma unroll
    for (int s = 0; s < NQ; ++s) {
        float4 v = redQ[s][l];
        ax += v.x; ay += v.y; az += v.z; aw += v.w;
    }
    {
        float af = av[l], bf = bv[l];
        float tvt = clip01(tvt_[l]);
        float rmax = af * (ay / ax);
        float rmin = af * (aw / az);
        r1s[l] = tvt * rmax + (1.0f - tvt) * rmin - bf;
    }

    // stage 2: lane l -> clause c = l&15, f-quarter j = l>>4
    {
        const int c = l & 15;
        const int j = l >> 4;
        float so = 0.f, wo = 0.f, sa = 0.f, wa = 0.f;
#pragma unroll
        for (int i = 0; i < 16; ++i) {
            int ff = j * 16 + i;
            float r1v = r1s[ff];
            float lg = __log2f(clip01(p1[c * NF + ff]) + EPSN);
            float z = KL * r1v;
            float eo = fexp2(z + lg);
            float ea = fexp2(lg - z);
            so += eo; wo = fmaf(eo, r1v, wo);
            sa += ea; wa = fmaf(ea, r1v, wa);
        }
#pragma unroll
        for (int d = 16; d < 64; d <<= 1) {
            so += __shfl_xor(so, d);
            wo += __shfl_xor(wo, d);
            sa += __shfl_xor(sa, d);
            wa += __shfl_xor(wa, d);
        }
        if (l < NC) {
            float tvl1 = clip01(tvl1_[l]);
            r2s[l] = tvl1 * (wo / so) + (1.0f - tvl1) * (wa / sa);
        }
    }

    // stage 3: lane 0
    if (l == 0) {
        float so = 0.f, wo = 0.f, sa = 0.f, wa = 0.f;
#pragma unroll
        for (int c = 0; c < NC; ++c) {
            float lg = __log2f(clip01(p2[c]) + EPSN);
            float r2v = r2s[c];
            float z = KL * r2v;
            float eo = fexp2(z + lg);
            float ea = fexp2(lg - z);
            so += eo; wo = fmaf(eo, r2v, wo);
            sa += ea; wa = fmaf(ea, r2v, wa);
        }
        float tvl2 = clip01(tvl2_[0]);
        out[b] = tvl2 * (wo / so) + (1.0f - tvl2) * (wa / sa);
    }
}

// ---------------------------------------------------------------------------
extern "C" void kernel_launch(void* const* d_in, const int* in_sizes, int n_in,
                              void* d_out, int out_size, void* d_ws, size_t ws_size,
                              hipStream_t stream) {
    const float* x    = (const float*)d_in[0];
    const float* t1   = (const float*)d_in[1];
    const float* t2   = (const float*)d_in[2];
    const float* a    = (const float*)d_in[3];
    const float* bv   = (const float*)d_in[4];
    const float* p1   = (const float*)d_in[5];
    const float* p2   = (const float*)d_in[6];
    const float* tvt  = (const float*)d_in[7];
    const float* tvl1 = (const float*)d_in[8];
    const float* tvl2 = (const float*)d_in[9];
    float* out = (float*)d_out;

    fused_kernel<<<BATCH, TPB, 0, stream>>>(x, t1, t2, a, bv, p1, p2,
                                            tvt, tvl1, tvl2, out);
}

// Round 7
// 26.096 us; speedup vs baseline: 8.5733x; 1.0308x over previous
//
#include <hip/hip_runtime.h>
#include <math.h>

#define NF 64
#define NC 16
#define LEN 2048
#define BATCH 256
#define BETA 2.5f
#define KAPPA 10.0f
#define EPSN 1e-12f
#define LOG2E 1.4426950408889634f

#define TPB 1024
#define NQ (TPB / NF)        // 16 waves per block
#define CHUNK (LEN / NQ)     // 128 t's per thread

__device__ __forceinline__ float clip01(float v) { return fminf(fmaxf(v, 0.0f), 1.0f); }

__device__ __forceinline__ float fexp2(float x) {
#if __has_builtin(__builtin_amdgcn_exp2f)
    return __builtin_amdgcn_exp2f(x);
#else
    return exp2f(x);
#endif
}

__device__ __forceinline__ float frcp(float x) {
#if __has_builtin(__builtin_amdgcn_rcpf)
    return __builtin_amdgcn_rcpf(x);
#else
    return 1.0f / x;
#endif
}

// ---------------------------------------------------------------------------
// Kernel 1: blocks 0..127 fill lwT4[g*NF+f].j = log2(w(f,4g+j)+eps)
// (coalesced float4 per thread); block 128 computes reg -> out[BATCH].
// ---------------------------------------------------------------------------
#define LW_BLOCKS ((NF * LEN / 4) / 256)   // 128

__global__ __launch_bounds__(256) void lw_reg_kernel(
    const float* __restrict__ t1, const float* __restrict__ t2,
    const float* __restrict__ p1, const float* __restrict__ p2,
    const float* __restrict__ tvt, const float* __restrict__ tvl1,
    const float* __restrict__ tvl2, float4* __restrict__ lwT4,
    float* __restrict__ out) {
    const int bid = blockIdx.x;
    const int tid = threadIdx.x;

    if (bid == LW_BLOCKS) {
        __shared__ float red[256];
        float acc = 0.0f;
        for (int i = tid; i < NC * NF; i += 256) {
            float p = clip01(p1[i]);
            acc += 0.01f * (p * (1.0f - p)) + 0.01f * (p * p);
        }
        if (tid < NC) {
            float p = clip01(p2[tid]);
            acc += 0.01f * (p * (1.0f - p)) + 0.01f * (p * p);
        }
        if (tid < NF) {
            float c = clip01(tvt[tid]);
            acc += 0.01f * (c * (1.0f - c));
        }
        if (tid < NC) {
            float c = clip01(tvl1[tid]);
            acc += 0.01f * (c * (1.0f - c));
        }
        if (tid == 0) {
            float c = clip01(tvl2[0]);
            acc += 0.01f * (c * (1.0f - c));
        }
        red[tid] = acc;
        __syncthreads();
        for (int s = 128; s > 0; s >>= 1) {
            if (tid < s) red[tid] += red[tid + s];
            __syncthreads();
        }
        if (tid == 0) out[BATCH] = red[0];
        return;
    }

    int idx = bid * 256 + tid;          // idx = g*NF + f
    int f = idx & (NF - 1);
    int g = idx >> 6;
    float t1c = fminf(fmaxf(t1[f], 0.0f), (float)(LEN - 1));
    float t2c = fminf(fmaxf(t2[f], 0.0f), (float)(LEN - 1));
    t1c = fminf(t1c, t2c - 1.0f);
    float4 r;
#pragma unroll
    for (int j = 0; j < 4; ++j) {
        float t = (float)(4 * g + j);
        float su = 1.0f / (1.0f + __expf(-BETA * (t - t1c)));
        float sv = 1.0f / (1.0f + __expf(-BETA * (t2c - t)));
        ((float*)&r)[j] = __log2f(su * sv + EPSN);
    }
    lwT4[idx] = r;
}

// ---------------------------------------------------------------------------
// Kernel 2: grid = BATCH x 1024 (16 waves), one block per batch element.
// stage1 inner loop: 2 exp2/element via the log2-domain table,
//   weights w*2^{+-A2*x} (b folded out; r = a*X/S - b recovered in finish).
// Per-wave partial -> LDS; one barrier; wave 0 runs the validated finish.
// ---------------------------------------------------------------------------
__global__ __launch_bounds__(TPB) void fused_main(
    const float* __restrict__ x, const float4* __restrict__ lwT4,
    const float* __restrict__ av, const float* __restrict__ bv,
    const float* __restrict__ p1, const float* __restrict__ p2,
    const float* __restrict__ tvt_, const float* __restrict__ tvl1_,
    const float* __restrict__ tvl2_, float* __restrict__ out) {
    __shared__ float4 redQ[NQ][NF];      // 16 KB
    __shared__ float r1s[NF];
    __shared__ float r2s[NC];

    const int b = blockIdx.x;
    const int tid = threadIdx.x;
    const int f = tid & (NF - 1);
    const int q = tid >> 6;
    const int ch = f & 1;

    const float B2 = BETA * LOG2E;
    const float KL = KAPPA * LOG2E;
    const float A2 = B2 * av[f];

    const int t0 = q * CHUNK;
    const float4* lw4 = lwT4 + (t0 >> 2) * NF + f;                     // per-lane
    const float4* xp4 = (const float4*)(x + (size_t)b * (LEN * 2) + 2 * t0); // uniform

    float Sp0 = 0.f, Xp0 = 0.f, Sm0 = 0.f, Xm0 = 0.f;
    float Sp1 = 0.f, Xp1 = 0.f, Sm1 = 0.f, Xm1 = 0.f;
#pragma unroll 4
    for (int g = 0; g < CHUNK / 4; ++g) {   // 4 t's per iteration
        float4 lw = lw4[g * NF];
        float4 u0 = xp4[2 * g];             // t = 4g, 4g+1
        float4 u1 = xp4[2 * g + 1];         // t = 4g+2, 4g+3
        float xa = ch ? u0.y : u0.x;
        float xb = ch ? u0.w : u0.z;
        float xc = ch ? u1.y : u1.x;
        float xd = ch ? u1.w : u1.z;
        float e;
        e = fexp2(fmaf(A2, xa, lw.x));  Sp0 += e; Xp0 = fmaf(e, xa, Xp0);
        e = fexp2(fmaf(-A2, xa, lw.x)); Sm0 += e; Xm0 = fmaf(e, xa, Xm0);
        e = fexp2(fmaf(A2, xb, lw.y));  Sp1 += e; Xp1 = fmaf(e, xb, Xp1);
        e = fexp2(fmaf(-A2, xb, lw.y)); Sm1 += e; Xm1 = fmaf(e, xb, Xm1);
        e = fexp2(fmaf(A2, xc, lw.z));  Sp0 += e; Xp0 = fmaf(e, xc, Xp0);
        e = fexp2(fmaf(-A2, xc, lw.z)); Sm0 += e; Xm0 = fmaf(e, xc, Xm0);
        e = fexp2(fmaf(A2, xd, lw.w));  Sp1 += e; Xp1 = fmaf(e, xd, Xp1);
        e = fexp2(fmaf(-A2, xd, lw.w)); Sm1 += e; Xm1 = fmaf(e, xd, Xm1);
    }

    redQ[q][f] = make_float4(Sp0 + Sp1, Xp0 + Xp1, Sm0 + Sm1, Xm0 + Xm1);
    __syncthreads();
    if (tid >= 64) return;

    // ---- finish: single wave (validated R5/R6) ----
    const int l = tid;
    float ax = 0.f, ay = 0.f, az = 0.f, aw = 0.f;
#pragma unroll
    for (int s = 0; s < NQ; ++s) {
        float4 v = redQ[s][l];
        ax += v.x; ay += v.y; az += v.z; aw += v.w;
    }
    {
        float af = av[l], bf = bv[l];
        float tvt = clip01(tvt_[l]);
        float rmax = af * (ay / ax);
        float rmin = af * (aw / az);
        r1s[l] = tvt * rmax + (1.0f - tvt) * rmin - bf;
    }

    // stage 2: lane l -> clause c = l&15, f-quarter j = l>>4
    {
        const int c = l & 15;
        const int j = l >> 4;
        float so = 0.f, wo = 0.f, sa = 0.f, wa = 0.f;
#pragma unroll
        for (int i = 0; i < 16; ++i) {
            int ff = j * 16 + i;
            float r1v = r1s[ff];
            float lg = __log2f(clip01(p1[c * NF + ff]) + EPSN);
            float z = KL * r1v;
            float eo = fexp2(z + lg);
            float ea = fexp2(lg - z);
            so += eo; wo = fmaf(eo, r1v, wo);
            sa += ea; wa = fmaf(ea, r1v, wa);
        }
#pragma unroll
        for (int d = 16; d < 64; d <<= 1) {
            so += __shfl_xor(so, d);
            wo += __shfl_xor(wo, d);
            sa += __shfl_xor(sa, d);
            wa += __shfl_xor(wa, d);
        }
        if (l < NC) {
            float tvl1 = clip01(tvl1_[l]);
            r2s[l] = tvl1 * (wo / so) + (1.0f - tvl1) * (wa / sa);
        }
    }

    // stage 3: lane 0
    if (l == 0) {
        float so = 0.f, wo = 0.f, sa = 0.f, wa = 0.f;
#pragma unroll
        for (int c = 0; c < NC; ++c) {
            float lg = __log2f(clip01(p2[c]) + EPSN);
            float r2v = r2s[c];
            float z = KL * r2v;
            float eo = fexp2(z + lg);
            float ea = fexp2(lg - z);
            so += eo; wo = fmaf(eo, r2v, wo);
            sa += ea; wa = fmaf(ea, r2v, wa);
        }
        float tvl2 = clip01(tvl2_[0]);
        out[b] = tvl2 * (wo / so) + (1.0f - tvl2) * (wa / sa);
    }
}

// ---------------------------------------------------------------------------
// Fallback: R6's validated single kernel (inline w), used when ws too small.
// ---------------------------------------------------------------------------
__global__ __launch_bounds__(TPB) void fused_inline(
    const float* __restrict__ x, const float* __restrict__ t1g,
    const float* __restrict__ t2g, const float* __restrict__ av,
    const float* __restrict__ bv, const float* __restrict__ p1,
    const float* __restrict__ p2, const float* __restrict__ tvt_,
    const float* __restrict__ tvl1_, const float* __restrict__ tvl2_,
    float* __restrict__ out) {
    __shared__ float4 redQ[NQ][NF];
    __shared__ float r1s[NF];
    __shared__ float r2s[NC];

    const int b = blockIdx.x;
    const int tid = threadIdx.x;
    const int f = tid & (NF - 1);
    const int q = tid >> 6;
    const int ch = f & 1;

    const float B2 = BETA * LOG2E;
    const float KL = KAPPA * LOG2E;
    const float A2 = B2 * av[f];

    float t1c = fminf(fmaxf(t1g[f], 0.0f), (float)(LEN - 1));
    float t2c = fminf(fmaxf(t2g[f], 0.0f), (float)(LEN - 1));
    t1c = fminf(t1c, t2c - 1.0f);
    const float c1 = B2 * t1c;
    const float c2 = -B2 * t2c;

    const int t0 = q * CHUNK;
    const float4* xp4 = (const float4*)(x + (size_t)b * (LEN * 2) + 2 * t0);

    float Sp0 = 0.f, Xp0 = 0.f, Sm0 = 0.f, Xm0 = 0.f;
    float Sp1 = 0.f, Xp1 = 0.f, Sm1 = 0.f, Xm1 = 0.f;
#pragma unroll 4
    for (int k2 = 0; k2 < CHUNK / 2; ++k2) {
        float4 v = xp4[k2];
        float xa = ch ? v.y : v.x;
        float xb = ch ? v.w : v.z;
        float tfa = (float)(t0 + 2 * k2);
        float tfb = tfa + 1.0f;
        {
            float g1 = fmaf(-B2, tfa, c1);
            float g2 = fmaf(B2, tfa, c2);
            float den = (1.0f + fexp2(g1)) * (1.0f + fexp2(g2));
            float w = frcp(den);
            float P = fexp2(A2 * xa);
            float Pm = frcp(P);
            float tp = P * w, tm = Pm * w;
            Sp0 += tp; Xp0 = fmaf(tp, xa, Xp0);
            Sm0 += tm; Xm0 = fmaf(tm, xa, Xm0);
        }
        {
            float g1 = fmaf(-B2, tfb, c1);
            float g2 = fmaf(B2, tfb, c2);
            float den = (1.0f + fexp2(g1)) * (1.0f + fexp2(g2));
            float w = frcp(den);
            float P = fexp2(A2 * xb);
            float Pm = frcp(P);
            float tp = P * w, tm = Pm * w;
            Sp1 += tp; Xp1 = fmaf(tp, xb, Xp1);
            Sm1 += tm; Xm1 = fmaf(tm, xb, Xm1);
        }
    }

    redQ[q][f] = make_float4(Sp0 + Sp1, Xp0 + Xp1, Sm0 + Sm1, Xm0 + Xm1);

    if (b == 0 && q == NQ - 1) {
        const int l = f;
        float acc = 0.0f;
#pragma unroll
        for (int i = 0; i < 16; ++i) {
            float p = clip01(p1[i * NF + l]);
            acc += 0.01f * (p * (1.0f - p)) + 0.01f * (p * p);
        }
        {
            float c = clip01(tvt_[l]);
            acc += 0.01f * (c * (1.0f - c));
        }
        if (l < NC) {
            float p = clip01(p2[l]);
            acc += 0.01f * (p * (1.0f - p)) + 0.01f * (p * p);
            float c = clip01(tvl1_[l]);
            acc += 0.01f * (c * (1.0f - c));
        }
        if (l == 0) {
            float c = clip01(tvl2_[0]);
            acc += 0.01f * (c * (1.0f - c));
        }
#pragma unroll
        for (int d = 1; d < 64; d <<= 1) acc += __shfl_xor(acc, d);
        if (l == 0) out[BATCH] = acc;
    }

    __syncthreads();
    if (tid >= 64) return;

    const int l = tid;
    float ax = 0.f, ay = 0.f, az = 0.f, aw = 0.f;
#pragma unroll
    for (int s = 0; s < NQ; ++s) {
        float4 v = redQ[s][l];
        ax += v.x; ay += v.y; az += v.z; aw += v.w;
    }
    {
        float af = av[l], bf = bv[l];
        float tvt = clip01(tvt_[l]);
        float rmax = af * (ay / ax);
        float rmin = af * (aw / az);
        r1s[l] = tvt * rmax + (1.0f - tvt) * rmin - bf;
    }
    {
        const int c = l & 15;
        const int j = l >> 4;
        float so = 0.f, wo = 0.f, sa = 0.f, wa = 0.f;
#pragma unroll
        for (int i = 0; i < 16; ++i) {
            int ff = j * 16 + i;
            float r1v = r1s[ff];
            float lg = __log2f(clip01(p1[c * NF + ff]) + EPSN);
            float z = KL * r1v;
            float eo = fexp2(z + lg);
            float ea = fexp2(lg - z);
            so += eo; wo = fmaf(eo, r1v, wo);
            sa += ea; wa = fmaf(ea, r1v, wa);
        }
#pragma unroll
        for (int d = 16; d < 64; d <<= 1) {
            so += __shfl_xor(so, d);
            wo += __shfl_xor(wo, d);
            sa += __shfl_xor(sa, d);
            wa += __shfl_xor(wa, d);
        }
        if (l < NC) {
            float tvl1 = clip01(tvl1_[l]);
            r2s[l] = tvl1 * (wo / so) + (1.0f - tvl1) * (wa / sa);
        }
    }
    if (l == 0) {
        float so = 0.f, wo = 0.f, sa = 0.f, wa = 0.f;
#pragma unroll
        for (int c = 0; c < NC; ++c) {
            float lg = __log2f(clip01(p2[c]) + EPSN);
            float r2v = r2s[c];
            float z = KL * r2v;
            float eo = fexp2(z + lg);
            float ea = fexp2(lg - z);
            so += eo; wo = fmaf(eo, r2v, wo);
            sa += ea; wa = fmaf(ea, r2v, wa);
        }
        float tvl2 = clip01(tvl2_[0]);
        out[b] = tvl2 * (wo / so) + (1.0f - tvl2) * (wa / sa);
    }
}

// ---------------------------------------------------------------------------
extern "C" void kernel_launch(void* const* d_in, const int* in_sizes, int n_in,
                              void* d_out, int out_size, void* d_ws, size_t ws_size,
                              hipStream_t stream) {
    const float* x    = (const float*)d_in[0];
    const float* t1   = (const float*)d_in[1];
    const float* t2   = (const float*)d_in[2];
    const float* a    = (const float*)d_in[3];
    const float* bv   = (const float*)d_in[4];
    const float* p1   = (const float*)d_in[5];
    const float* p2   = (const float*)d_in[6];
    const float* tvt  = (const float*)d_in[7];
    const float* tvl1 = (const float*)d_in[8];
    const float* tvl2 = (const float*)d_in[9];
    float* out = (float*)d_out;

    const size_t lw_bytes = (size_t)(NF * LEN) * sizeof(float);   // 512 KB

    if (d_ws && ws_size >= lw_bytes) {
        float4* lwT4 = (float4*)d_ws;
        lw_reg_kernel<<<LW_BLOCKS + 1, 256, 0, stream>>>(t1, t2, p1, p2, tvt, tvl1,
                                                         tvl2, lwT4, out);
        fused_main<<<BATCH, TPB, 0, stream>>>(x, lwT4, a, bv, p1, p2,
                                              tvt, tvl1, tvl2, out);
    } else {
        fused_inline<<<BATCH, TPB, 0, stream>>>(x, t1, t2, a, bv, p1, p2,
                                                tvt, tvl1, tvl2, out);
    }
}